// Round 3
// baseline (605.610 us; speedup 1.0000x reference)
//
#include <hip/hip_runtime.h>
#include <math.h>

#define L 1632
#define NUP 8
#define NB 32
#define NA 64
#define KK 12
#define NW 21          // 2*SEARCH+1
#define RED 408        // L/LOCC
#define WS 408         // s-dimension of decimated DFT (L/4)
#define WIM (NW*WS)    // offset of imag plane in WT

// ---------------------------------------------------------------------------
// Kernel 1: one block per (u,b). Decimated window DFT:
//   n = 408q + s,  X(t) = sum_s e^{i th s t} * G_s(t mod 4),
//   G_s(tau) = sum_q x_{408q+s} i^{q tau}   (4-pt DFT, adds only).
// W[o][s] = e^{i th s (t0+o)} precomputed in LDS, shared by all 64 antennas.
// 8 waves; wave w handles antennas 8w..8w+7. Lane l owns s-quads 4l (j=0)
// and 256+4l (j=1, lanes 0..37). Noise diff power folded into same pass.
// ---------------------------------------------------------------------------
__global__ __launch_bounds__(512, 2) void k1_window(
    const float* __restrict__ lsr, const float* __restrict__ lsi,
    const int* __restrict__ cshift,
    float* __restrict__ winp, float* __restrict__ noisep)
{
    const int ub   = blockIdx.x;          // u*32 + b
    const int u    = ub >> 5;
    const int tid  = threadIdx.x;
    const int wave = tid >> 6;
    const int lane = tid & 63;

    __shared__ float WT[2 * NW * WS];     // [re|im][o][s] : 68544 B
    __shared__ float win[NW];
    __shared__ float nshared;

    const int shift = cshift[u];
    const int ip    = ((KK - shift) % KK) * (L / KK);
    int t0 = ip - 10;
    t0 = ((t0 % L) + L) % L;

    const float cph = (float)(2.0 * M_PI / (double)L);

    // ---- precompute W ----
    for (int f = tid; f < NW * WS; f += 512) {
        const int o = f / WS;
        const int s = f - o * WS;
        const int t = (t0 + o) % L;
        const int idx = (s * t) % L;      // < 1632*1632 < 2^31
        float sn, cs;
        __sincosf(cph * (float)idx, &sn, &cs);
        WT[f]       = cs;
        WT[WIM + f] = sn;
    }
    if (tid < NW)  win[tid] = 0.0f;
    if (tid == NW) nshared = 0.0f;
    __syncthreads();

    const int c4 = t0 & 3;

    float winacc[NW];
#pragma unroll
    for (int o = 0; o < NW; o++) winacc[o] = 0.0f;
    float na = 0.0f;

    for (int i = 0; i < 8; i++) {
        const int a   = wave * 8 + i;
        const int row = (ub * NA + a) * L;

        float accr[NW], acci[NW];
#pragma unroll
        for (int o = 0; o < NW; o++) { accr[o] = 0.0f; acci[o] = 0.0f; }

        float s255r[4], s255i[4], s0r[4], s0i[4], s407r[4], s407i[4];

        for (int j = 0; j < 2; j++) {
            const int  nact = j ? 38 : 64;
            const bool act  = lane < nact;
            const int  s0   = 256 * j + 4 * lane;
            const int  sc   = act ? s0 : 0;      // clamped (safe LDS addr)

            float exr[4][4], exi[4][4];          // [q][e]
#pragma unroll
            for (int q = 0; q < 4; q++) {
#pragma unroll
                for (int e = 0; e < 4; e++) { exr[q][e] = 0.0f; exi[q][e] = 0.0f; }
                if (act) {
                    const float4 r4 = *reinterpret_cast<const float4*>(lsr + row + 408 * q + s0);
                    const float4 i4 = *reinterpret_cast<const float4*>(lsi + row + 408 * q + s0);
                    exr[q][0] = r4.x; exr[q][1] = r4.y; exr[q][2] = r4.z; exr[q][3] = r4.w;
                    exi[q][0] = i4.x; exi[q][1] = i4.y; exi[q][2] = i4.z; exi[q][3] = i4.w;
                }
            }

            // ---- noise: within-quad diffs ----
            if (act) {
#pragma unroll
                for (int q = 0; q < 4; q++) {
                    float dr, di;
                    dr = exr[q][1] - exr[q][0]; di = exi[q][1] - exi[q][0]; na += dr * dr + di * di;
                    dr = exr[q][2] - exr[q][1]; di = exi[q][2] - exi[q][1]; na += dr * dr + di * di;
                    dr = exr[q][3] - exr[q][2]; di = exi[q][3] - exi[q][2]; na += dr * dr + di * di;
                }
            }
            // ---- noise: quad-boundary diffs + stashes ----
#pragma unroll
            for (int q = 0; q < 4; q++) {
                const float pr = __shfl_up(exr[q][3], 1);
                const float pi = __shfl_up(exi[q][3], 1);
                if (j == 0) {
                    if (lane > 0) {
                        const float dr = exr[q][0] - pr, di = exi[q][0] - pi;
                        na += dr * dr + di * di;
                    }
                    s255r[q] = __shfl(exr[q][3], 63); s255i[q] = __shfl(exi[q][3], 63);
                    s0r[q]   = __shfl(exr[q][0], 0);  s0i[q]   = __shfl(exi[q][0], 0);
                } else {
                    const float qr = (lane == 0) ? s255r[q] : pr;
                    const float qi = (lane == 0) ? s255i[q] : pi;
                    if (act) {
                        const float dr = exr[q][0] - qr, di = exi[q][0] - qi;
                        na += dr * dr + di * di;
                    }
                    s407r[q] = __shfl(exr[q][3], 37); s407i[q] = __shfl(exi[q][3], 37);
                }
            }

            // ---- 4-pt DFT across quarters (adds only) ----
            float Gr[4][4], Gi[4][4];            // [e][tau]
#pragma unroll
            for (int e = 0; e < 4; e++) {
                const float x0r = exr[0][e], x0i = exi[0][e];
                const float x1r = exr[1][e], x1i = exi[1][e];
                const float x2r = exr[2][e], x2i = exi[2][e];
                const float x3r = exr[3][e], x3i = exi[3][e];
                const float ar = x0r + x2r, ai = x0i + x2i;
                const float br = x0r - x2r, bi = x0i - x2i;
                const float cr = x1r + x3r, ci = x1i + x3i;
                const float dr = x1r - x3r, di = x1i - x3i;
                Gr[e][0] = ar + cr; Gi[e][0] = ai + ci;
                Gr[e][2] = ar - cr; Gi[e][2] = ai - ci;
                Gr[e][1] = br - di; Gi[e][1] = bi + dr;   // b + i*d
                Gr[e][3] = br + di; Gi[e][3] = bi - dr;   // b - i*d
            }

            // ---- uniform relabel so tau index is compile-time: H[e][k]=G[e][(k+c4)&3]
            float Hr[4][4], Hi[4][4];
#define RELAB(C) { _Pragma("unroll") \
            for (int e = 0; e < 4; e++) { \
                Hr[e][0] = Gr[e][(0+(C))&3]; Hi[e][0] = Gi[e][(0+(C))&3]; \
                Hr[e][1] = Gr[e][(1+(C))&3]; Hi[e][1] = Gi[e][(1+(C))&3]; \
                Hr[e][2] = Gr[e][(2+(C))&3]; Hi[e][2] = Gi[e][(2+(C))&3]; \
                Hr[e][3] = Gr[e][(3+(C))&3]; Hi[e][3] = Gi[e][(3+(C))&3]; } }
            switch (c4) {
                case 0: RELAB(0); break;
                case 1: RELAB(1); break;
                case 2: RELAB(2); break;
                default: RELAB(3); break;
            }
#undef RELAB

            // ---- outer stage: 21 complex MACs per quad, weights from LDS ----
#pragma unroll
            for (int o = 0; o < NW; o++) {
                const int tau = o & 3;
                const float4 wr4 = *reinterpret_cast<const float4*>(&WT[o * WS + sc]);
                const float4 wi4 = *reinterpret_cast<const float4*>(&WT[WIM + o * WS + sc]);
                accr[o] += wr4.x * Hr[0][tau] - wi4.x * Hi[0][tau]
                         + wr4.y * Hr[1][tau] - wi4.y * Hi[1][tau]
                         + wr4.z * Hr[2][tau] - wi4.z * Hi[2][tau]
                         + wr4.w * Hr[3][tau] - wi4.w * Hi[3][tau];
                acci[o] += wr4.x * Hi[0][tau] + wi4.x * Hr[0][tau]
                         + wr4.y * Hi[1][tau] + wi4.y * Hr[1][tau]
                         + wr4.z * Hi[2][tau] + wi4.z * Hr[2][tau]
                         + wr4.w * Hi[3][tau] + wi4.w * Hr[3][tau];
            }
        }

        // deferred quarter-boundary noise diffs (n = 408q, q>=1)
        if (lane == 0) {
#pragma unroll
            for (int q = 1; q < 4; q++) {
                const float dr = s0r[q] - s407r[q - 1];
                const float di = s0i[q] - s407i[q - 1];
                na += dr * dr + di * di;
            }
        }

        // wave butterfly reduction of the 21 complex bins
#pragma unroll
        for (int m = 1; m < 64; m <<= 1) {
#pragma unroll
            for (int o = 0; o < NW; o++) {
                accr[o] += __shfl_xor(accr[o], m);
                acci[o] += __shfl_xor(acci[o], m);
            }
        }
#pragma unroll
        for (int o = 0; o < NW; o++)
            winacc[o] += accr[o] * accr[o] + acci[o] * acci[o];
    }

#pragma unroll
    for (int m = 1; m < 64; m <<= 1) na += __shfl_xor(na, m);

    if (lane == 0) {
        atomicAdd(&nshared, na);
#pragma unroll
        for (int o = 0; o < NW; o++) atomicAdd(&win[o], winacc[o]);
    }
    __syncthreads();
    if (tid < NW)  winp[ub * NW + tid] = win[tid];
    if (tid == 0)  noisep[ub] = nshared;
}

// ---------------------------------------------------------------------------
// Kernel 2: per (u,b): argmax of window -> mm; noise_pw; Gauss-Jordan inverse
// of (C + s*I) in LDS; W = C @ inv. Grid: 256 blocks, 192 threads.
// ---------------------------------------------------------------------------
__global__ __launch_bounds__(192) void k2_wmat(
    const float* __restrict__ winp, const float* __restrict__ noisep,
    const int* __restrict__ cshift,
    float* __restrict__ Wout, int* __restrict__ mmOut)
{
    const int ub  = blockIdx.x;
    const int u   = ub >> 5;
    const int tid = threadIdx.x;
    __shared__ float win[NW];
    __shared__ float Cs[12][12];
    __shared__ float aug[12][25];
    __shared__ float snoise;

    if (tid < NW) win[tid] = winp[ub * NW + tid];
    if (tid == NW) snoise = noisep[ub] / (float)NA / (float)(L - 1) / 2.0f;
    if (tid >= 32 && tid < 32 + 144) {
        const int t = tid - 32;
        const int i = t / 12, j = t % 12;
        const int d = (i > j) ? (i - j) : (j - i);
        double v = 1.0;
        for (int k = 0; k < d; k++) v *= 0.9;   // RHO^|i-j|
        Cs[i][j] = (float)v;
    }
    __syncthreads();

    if (tid < 144) {
        const int i = tid / 12, j = tid % 12;
        aug[i][j]      = Cs[i][j] + ((i == j) ? snoise : 0.0f);
        aug[i][12 + j] = (i == j) ? 1.0f : 0.0f;
    }
    __syncthreads();

    for (int k = 0; k < 12; k++) {
        float pv = 1.0f, rowkj = 0.0f;
        float fcol[12];
        if (tid < 24) {
            pv    = aug[k][k];
            rowkj = aug[k][tid];
#pragma unroll
            for (int i = 0; i < 12; i++) fcol[i] = aug[i][k];
        }
        __syncthreads();
        if (tid < 24) {
            const float nrm = rowkj / pv;
            aug[k][tid] = nrm;
#pragma unroll
            for (int i = 0; i < 12; i++)
                if (i != k) aug[i][tid] -= fcol[i] * nrm;
        }
        __syncthreads();
    }

    if (tid == 0) {
        float best = win[0];
        int bo = 0;
        for (int o = 1; o < NW; o++)
            if (win[o] > best) { best = win[o]; bo = o; }
        const int shift = cshift[u];
        const int ip = ((KK - shift) % KK) * (L / KK);
        const int m = ip + (bo - 10);
        mmOut[ub] = ((m % L) + L) % L;
    }

    if (tid < 144) {
        const int i = tid / 12, j = tid % 12;
        float w = 0.0f;
#pragma unroll
        for (int k = 0; k < 12; k++) w += Cs[i][k] * aug[k][12 + j];
        Wout[ub * 144 + tid] = w;
    }
}

// ---------------------------------------------------------------------------
// Kernel 3: per (u,b,a) row: phase-rotate, 4-average, linear interp, 12x12
// Wiener smoothing, write interleaved re/im. Grid: 16384 blocks, 256 threads.
// ---------------------------------------------------------------------------
__global__ __launch_bounds__(256) void k3_main(
    const float* __restrict__ lsr, const float* __restrict__ lsi,
    const float* __restrict__ Wall, const int* __restrict__ mmArr,
    float* __restrict__ out)
{
    const int bid = blockIdx.x;     // (u*32+b)*64 + a
    const int ub  = bid >> 6;
    const int row = bid * L;
    const int tid = threadIdx.x;
    __shared__ float2 havg[RED];
    __shared__ float2 hint[L];
    __shared__ float  Wl[144];
    if (tid < 144) Wl[tid] = Wall[ub * 144 + tid];
    const int mm = mmArr[ub];
    const float cph = (float)(2.0 * M_PI / (double)L);

    for (int r = tid; r < RED; r += 256) {
        const int base = 4 * r;
        const float4 xr = *reinterpret_cast<const float4*>(lsr + row + base);
        const float4 xi = *reinterpret_cast<const float4*>(lsi + row + base);
        int idx = (mm * base) % L;
        float ar = 0.0f, ai = 0.0f, sn, cs;
        __sincosf(cph * (float)idx, &sn, &cs);
        ar += xr.x * cs - xi.x * sn; ai += xr.x * sn + xi.x * cs;
        idx += mm; if (idx >= L) idx -= L;
        __sincosf(cph * (float)idx, &sn, &cs);
        ar += xr.y * cs - xi.y * sn; ai += xr.y * sn + xi.y * cs;
        idx += mm; if (idx >= L) idx -= L;
        __sincosf(cph * (float)idx, &sn, &cs);
        ar += xr.z * cs - xi.z * sn; ai += xr.z * sn + xi.z * cs;
        idx += mm; if (idx >= L) idx -= L;
        __sincosf(cph * (float)idx, &sn, &cs);
        ar += xr.w * cs - xi.w * sn; ai += xr.w * sn + xi.w * cs;
        havg[r] = make_float2(ar * 0.25f, ai * 0.25f);
    }
    __syncthreads();

    for (int t = tid; t < L; t += 256) {
        float p = ((float)t - 1.5f) * 0.25f;
        p = fminf(fmaxf(p, 0.0f), 407.0f);
        int i0 = (int)p;
        if (i0 > 406) i0 = 406;
        const float fr = p - (float)i0;
        const float2 h0 = havg[i0], h1 = havg[i0 + 1];
        hint[t] = make_float2(h0.x * (1.0f - fr) + h1.x * fr,
                              h0.y * (1.0f - fr) + h1.y * fr);
    }
    __syncthreads();

    float2* o2 = reinterpret_cast<float2*>(out);
    for (int e = tid; e < L; e += 256) {
        const int j = e / 12;
        const int i = e - j * 12;
        const float* wr = &Wl[i * 12];
        float ax = 0.0f, ay = 0.0f;
#pragma unroll
        for (int k = 0; k < 12; k++) {
            const float  w = wr[k];
            const float2 h = hint[j * 12 + k];
            ax += w * h.x; ay += w * h.y;
        }
        o2[row + e] = make_float2(ax, ay);
    }
}

// ---------------------------------------------------------------------------
extern "C" void kernel_launch(void* const* d_in, const int* in_sizes, int n_in,
                              void* d_out, int out_size, void* d_ws, size_t ws_size,
                              hipStream_t stream) {
    const float* lsr    = (const float*)d_in[0];
    const float* lsi    = (const float*)d_in[1];
    const int*   cshift = (const int*)d_in[2];
    float* out = (float*)d_out;

    char* ws = (char*)d_ws;
    float* Wout   = (float*)(ws);                          // 256*144*4 = 147456 B
    float* winp   = (float*)(ws + 147456);                 // 256*21*4  =  21504 B
    float* noisep = (float*)(ws + 147456 + 21504);         // 256*4     =   1024 B
    int*   mmArr  = (int*)  (ws + 147456 + 21504 + 1024);  // 256*4     =   1024 B

    hipLaunchKernelGGL(k1_window, dim3(NUP * NB), dim3(512), 0, stream,
                       lsr, lsi, cshift, winp, noisep);
    hipLaunchKernelGGL(k2_wmat, dim3(NUP * NB), dim3(192), 0, stream,
                       winp, noisep, cshift, Wout, mmArr);
    hipLaunchKernelGGL(k3_main, dim3(NUP * NB * NA), dim3(256), 0, stream,
                       lsr, lsi, Wout, mmArr, out);
}